// Round 10
// baseline (109.197 us; speedup 1.0000x reference)
//
#include <hip/hip_runtime.h>
#include <hip/hip_bf16.h>

#define B_TOT  1024
#define IN_DIM 512
#define C_DIM  128
#define HID    128
#define EMB    32
#define NKT    8               // K-steps of 64

#define XS_LD 68
#define W1_LD 68
#define HS_LD 132
#define W2_LD 132

using bf16x8 = __attribute__((ext_vector_type(8))) short;
using f32x4  = __attribute__((ext_vector_type(4))) float;

__device__ __forceinline__ unsigned short f2b(float f) {
    union { __hip_bfloat16 h; unsigned short u; } cv;
    cv.h = __float2bfloat16(f);
    return cv.u;
}
__device__ __forceinline__ unsigned int pack2(float a, float b) {
    return (unsigned int)f2b(a) | ((unsigned int)f2b(b) << 16);
}
__device__ __forceinline__ unsigned long long pack4(float a, float b, float c, float d) {
    return (unsigned long long)pack2(a, b) | ((unsigned long long)pack2(c, d) << 32);
}
__device__ __forceinline__ bf16x8 load8u(const unsigned short* p) {
    union { unsigned long long q[2]; bf16x8 v; } u;
    u.q[0] = *(const unsigned long long*)(p);
    u.q[1] = *(const unsigned long long*)(p + 4);
    return u.v;
}

// Round-1 structure (proven 2.44 TB/s sustained), ONE change: c-grouped XCD
// mapping so the 8 btile-siblings sharing W1[c] run on the SAME XCD ->
// W1 re-reads become L2/L3 hits instead of 8x HBM streams.
__global__ __launch_bounds__(256, 2) void bank_fused(
    const float* __restrict__ x,
    const float* __restrict__ pW1, const float* __restrict__ pb1,
    const float* __restrict__ pW2, const float* __restrict__ pb2,
    const float* __restrict__ nW1, const float* __restrict__ nb1,
    const float* __restrict__ nW2, const float* __restrict__ nb2,
    float* __restrict__ out)
{
    __shared__ unsigned short Xs [128][XS_LD];   // X tile, bf16, [b][k]
    __shared__ unsigned short W1T[HID][W1_LD];   // W1 tile transposed, [h][k]
    __shared__ unsigned short Hs [128][HS_LD];   // relu(h) tile, [b][h]
    __shared__ unsigned short W2T[EMB][W2_LD];   // W2 transposed, [e][h]

    // mapping: xcd = p&7; c = xcd*16 + (rank&15)  (16 c's per XCD: output-line
    // write merge); btile = (rank>>4)&7 (W1[c] reuse within XCD across
    // generations); bank = rank>>7.
    const int p     = blockIdx.x;
    const int xcd   = p & 7;
    const int rank  = p >> 3;
    const int c     = xcd * 16 + (rank & 15);
    const int btile = (rank >> 4) & 7;
    const int bank  = rank >> 7;
    const int bbase = btile * 128;

    const float* W1c = (bank ? nW1 : pW1) + (size_t)c * IN_DIM * HID;
    const float* b1c = (bank ? nb1 : pb1) + c * HID;
    const float* W2c = (bank ? nW2 : pW2) + (size_t)c * HID * EMB;
    const float* b2c = (bank ? nb2 : pb2) + c * EMB;
    float* outb = out + (size_t)bank * B_TOT * EMB * C_DIM;

    const int t    = threadIdx.x;
    const int wave = t >> 6;
    const int lane = t & 63;
    const int lr   = lane & 15;
    const int lkg  = lane >> 4;
    const int wm   = wave >> 1;
    const int wn   = wave & 1;

    // stage W2 transposed (once per block)
    {
        int e0 = (t & 7) * 4, h0 = (t >> 3) * 4;
        f32x4 L0 = *(const f32x4*)&W2c[(h0 + 0) * EMB + e0];
        f32x4 L1 = *(const f32x4*)&W2c[(h0 + 1) * EMB + e0];
        f32x4 L2 = *(const f32x4*)&W2c[(h0 + 2) * EMB + e0];
        f32x4 L3 = *(const f32x4*)&W2c[(h0 + 3) * EMB + e0];
#pragma unroll
        for (int j = 0; j < 4; ++j)
            *(unsigned long long*)&W2T[e0 + j][h0] = pack4(L0[j], L1[j], L2[j], L3[j]);
    }

    float b1v[4];
#pragma unroll
    for (int ni = 0; ni < 4; ++ni) b1v[ni] = b1c[wn * 64 + ni * 16 + lr];
    float b2v[2];
#pragma unroll
    for (int ei = 0; ei < 2; ++ei) b2v[ei] = b2c[ei * 16 + lr];

    f32x4 acc[4][4];
#pragma unroll
    for (int mi = 0; mi < 4; ++mi)
#pragma unroll
        for (int ni = 0; ni < 4; ++ni) acc[mi][ni] = (f32x4){0.f, 0.f, 0.f, 0.f};

    // ================= GEMM1: H = relu(X * W1 + b1), K = 512 ================
    for (int kt = 0; kt < NKT; ++kt) {
        int kb = kt * 64;

        // stage X tile [128][64]: 8 float4 loads per thread (high MLP)
#pragma unroll
        for (int w8 = 0; w8 < 8; ++w8) {
            int f   = w8 * 256 + t;
            int row = f >> 4;
            int col = (f & 15) * 4;
            f32x4 v = *(const f32x4*)&x[(size_t)(bbase + row) * IN_DIM + kb + col];
            *(unsigned long long*)&Xs[row][col] = pack4(v[0], v[1], v[2], v[3]);
        }
        // stage W1 tile [64][128] transposed -> W1T[h][k]: 8 float4 loads/thread
#pragma unroll
        for (int g = 0; g < 2; ++g) {
            int s  = g * 256 + t;
            int kg = s >> 5;
            int hg = s & 31;
            int k0 = kg * 4, h0 = hg * 4;
            const float* src = &W1c[(size_t)(kb + k0) * HID + h0];
            f32x4 L0 = *(const f32x4*)(src + 0 * HID);
            f32x4 L1 = *(const f32x4*)(src + 1 * HID);
            f32x4 L2 = *(const f32x4*)(src + 2 * HID);
            f32x4 L3 = *(const f32x4*)(src + 3 * HID);
#pragma unroll
            for (int j = 0; j < 4; ++j) {
                *(unsigned long long*)&W1T[h0 + j][k0] = pack4(L0[j], L1[j], L2[j], L3[j]);
            }
        }
        __syncthreads();

#pragma unroll
        for (int ki = 0; ki < 2; ++ki) {
            int kcol = ki * 32 + lkg * 8;
            bf16x8 af[4], bfr[4];
#pragma unroll
            for (int mi = 0; mi < 4; ++mi)
                af[mi] = load8u(&Xs[wm * 64 + mi * 16 + lr][kcol]);
#pragma unroll
            for (int ni = 0; ni < 4; ++ni)
                bfr[ni] = load8u(&W1T[wn * 64 + ni * 16 + lr][kcol]);
#pragma unroll
            for (int mi = 0; mi < 4; ++mi)
#pragma unroll
                for (int ni = 0; ni < 4; ++ni)
                    acc[mi][ni] = __builtin_amdgcn_mfma_f32_16x16x32_bf16(
                        af[mi], bfr[ni], acc[mi][ni], 0, 0, 0);
        }
        __syncthreads();
    }

    // epilogue1: bias + relu + bf16 -> Hs[b][h]
#pragma unroll
    for (int mi = 0; mi < 4; ++mi) {
        int row = wm * 64 + mi * 16 + lkg * 4;
#pragma unroll
        for (int ni = 0; ni < 4; ++ni) {
            int col = wn * 64 + ni * 16 + lr;
#pragma unroll
            for (int j = 0; j < 4; ++j) {
                float v = acc[mi][ni][j] + b1v[ni];
                Hs[row + j][col] = f2b(fmaxf(v, 0.f));
            }
        }
    }
    __syncthreads();

    // ================= GEMM2: out = H * W2 + b2 (M=128,N=32,K=128) ==========
    f32x4 acc2[2][2];
#pragma unroll
    for (int m2 = 0; m2 < 2; ++m2)
#pragma unroll
        for (int ei = 0; ei < 2; ++ei) acc2[m2][ei] = (f32x4){0.f, 0.f, 0.f, 0.f};

    const int rb = wave * 32;
#pragma unroll
    for (int k2 = 0; k2 < 4; ++k2) {
        int kcol = k2 * 32 + lkg * 8;
        bf16x8 a2[2], b2f[2];
#pragma unroll
        for (int m2 = 0; m2 < 2; ++m2)
            a2[m2] = load8u(&Hs[rb + m2 * 16 + lr][kcol]);
#pragma unroll
        for (int ei = 0; ei < 2; ++ei)
            b2f[ei] = load8u(&W2T[ei * 16 + lr][kcol]);
#pragma unroll
        for (int m2 = 0; m2 < 2; ++m2)
#pragma unroll
            for (int ei = 0; ei < 2; ++ei)
                acc2[m2][ei] = __builtin_amdgcn_mfma_f32_16x16x32_bf16(
                    a2[m2], b2f[ei], acc2[m2][ei], 0, 0, 0);
    }

    // stores: out[b][e][c] fp32 (16-c lines merge within this XCD's L2)
#pragma unroll
    for (int m2 = 0; m2 < 2; ++m2) {
#pragma unroll
        for (int ei = 0; ei < 2; ++ei) {
            int e = ei * 16 + lr;
#pragma unroll
            for (int j = 0; j < 4; ++j) {
                int brow = bbase + rb + m2 * 16 + lkg * 4 + j;
                outb[((size_t)brow * EMB + e) * C_DIM + c] = acc2[m2][ei][j] + b2v[ei];
            }
        }
    }
}

extern "C" void kernel_launch(void* const* d_in, const int* in_sizes, int n_in,
                              void* d_out, int out_size, void* d_ws, size_t ws_size,
                              hipStream_t stream) {
    const float* x   = (const float*)d_in[0];
    const float* pW1 = (const float*)d_in[1];
    const float* pb1 = (const float*)d_in[2];
    const float* pW2 = (const float*)d_in[3];
    const float* pb2 = (const float*)d_in[4];
    const float* nW1 = (const float*)d_in[5];
    const float* nb1 = (const float*)d_in[6];
    const float* nW2 = (const float*)d_in[7];
    const float* nb2 = (const float*)d_in[8];
    float* out = (float*)d_out;

    bank_fused<<<dim3(2048), dim3(256), 0, stream>>>(
        x, pW1, pb1, pW2, pb2, nW1, nb1, nW2, nb2, out);
}

// Round 11
// 89.610 us; speedup vs baseline: 1.2186x; 1.2186x over previous
//
#include <hip/hip_runtime.h>
#include <hip/hip_bf16.h>

#define B_TOT  1024
#define IN_DIM 512
#define C_DIM  128
#define HID    128
#define EMB    32
#define BK     32
#define NKT    (IN_DIM / BK)   // 16

// workspace layout (ushort indices) — all operands FRAGMENT-PACKED:
//  W1: ws[pair*65536 + kt*4096 + nfrag*512 + lane*8 + kin]
//      lane = lkg*16 + (h&15), holds W1[k0+lkg*8+kin][h]
//  W2: WS_W2_OFF + pair*4096 + k2*1024 + ei*512 + lane*8 + kin
//  X : WS_X_OFF + rowblk128*65536 + kt*4096 + mfrag*512 + lane*8 + kin
//      lane = lkg*16 + (row&15), holds x[row][kt*32+lkg*8+kin]
#define WS_W1_STRIDE 65536ull
#define WS_W2_OFF    16777216ull
#define WS_X_OFF     17825792ull
#define WS_NEEDED_B  36700160ull               // bytes

using bf16x8 = __attribute__((ext_vector_type(8))) short;
using f32x4  = __attribute__((ext_vector_type(4))) float;

__device__ __forceinline__ unsigned short f2b(float f) {
    union { __hip_bfloat16 h; unsigned short u; } cv;
    cv.h = __float2bfloat16(f);
    return cv.u;
}
__device__ __forceinline__ unsigned int pack2(float a, float b) {
    return (unsigned int)f2b(a) | ((unsigned int)f2b(b) << 16);
}
__device__ __forceinline__ unsigned long long pack4(float a, float b, float c, float d) {
    return (unsigned long long)pack2(a, b) | ((unsigned long long)pack2(c, d) << 32);
}
__device__ __forceinline__ bf16x8 ld16(const unsigned short* p) {
    return *(const bf16x8*)p;
}
__device__ __forceinline__ void g2l16(const unsigned short* g, unsigned short* l) {
    __builtin_amdgcn_global_load_lds(
        (const __attribute__((address_space(1))) unsigned int*)(g),
        (__attribute__((address_space(3))) unsigned int*)(l), 16, 0, 0);
}

// ============================ prepass ============================
// 1024 blocks x 256 thr. pair = blk>>2, quarter = blk&3; x-row = blk.
__global__ __launch_bounds__(256) void prepass(
    const float* __restrict__ x,
    const float* __restrict__ pW1, const float* __restrict__ pW2,
    const float* __restrict__ nW1, const float* __restrict__ nW2,
    unsigned short* __restrict__ ws)
{
    __shared__ unsigned short img[4096];   // 8 KB
    const int blk     = blockIdx.x;
    const int pair    = blk >> 2;          // bank*128 + c
    const int quarter = blk & 3;
    const int bank    = pair >> 7;
    const int c       = pair & 127;
    const int t       = threadIdx.x;

    const float* W1c = (bank ? nW1 : pW1) + (size_t)c * IN_DIM * HID;
    const float* W2c = (bank ? nW2 : pW2) + (size_t)c * HID * EMB;

    // ---- W2 (quarter 0 only): frag-pack ----
    if (quarter == 0) {
        int e0 = (t & 7) * 4, h0 = (t >> 3) * 4;
        const float* src = &W2c[(size_t)h0 * EMB + e0];
        f32x4 L0 = *(const f32x4*)(src + 0 * EMB);
        f32x4 L1 = *(const f32x4*)(src + 1 * EMB);
        f32x4 L2 = *(const f32x4*)(src + 2 * EMB);
        f32x4 L3 = *(const f32x4*)(src + 3 * EMB);
        unsigned short* dst = ws + WS_W2_OFF + (size_t)pair * 4096;
#pragma unroll
        for (int j = 0; j < 4; ++j) {
            int e = e0 + j;
            int idx = (h0 >> 5) * 1024 + (e >> 4) * 512 +
                      ((((h0 & 31) >> 3) * 16 + (e & 15)) * 8) + (h0 & 7);
            *(unsigned long long*)&dst[idx] = pack4(L0[j], L1[j], L2[j], L3[j]);
        }
    }

    // ---- W1: four 32-k chunks per block, frag-packed via img ----
#pragma unroll
    for (int q = 0; q < 4; ++q) {
        const int kt = quarter * 4 + q;
        const float* Wk = W1c + (size_t)kt * BK * HID;
        {
            int k0 = (t >> 5) * 4;       // 0..28
            int h0 = (t & 31) * 4;       // 0..124
            const float* src = &Wk[(size_t)k0 * HID + h0];
            f32x4 L0 = *(const f32x4*)(src + 0 * HID);
            f32x4 L1 = *(const f32x4*)(src + 1 * HID);
            f32x4 L2 = *(const f32x4*)(src + 2 * HID);
            f32x4 L3 = *(const f32x4*)(src + 3 * HID);
#pragma unroll
            for (int j = 0; j < 4; ++j) {
                int h = h0 + j;
                int idx = (h >> 4) * 512 +
                          (((k0 >> 3) * 16 + (h & 15)) * 8) + (k0 & 7);
                *(unsigned long long*)&img[idx] = pack4(L0[j], L1[j], L2[j], L3[j]);
            }
        }
        __syncthreads();
        unsigned short* dst = ws + (size_t)pair * WS_W1_STRIDE + (size_t)kt * 4096;
        *(bf16x8*)&dst[t * 16]     = *(const bf16x8*)&img[t * 16];
        *(bf16x8*)&dst[t * 16 + 8] = *(const bf16x8*)&img[t * 16 + 8];
        __syncthreads();
    }

    // ---- x: one row per block, frag-packed (8B scatter, one-time cost) ----
    {
        const int row = blk;              // 0..1023
        if (t < 128) {
            int k0 = t * 4;
            f32x4 v = *(const f32x4*)&x[(size_t)row * IN_DIM + k0];
            size_t idx = WS_X_OFF + (size_t)(row >> 7) * 65536 +
                         (size_t)(k0 >> 5) * 4096 + (size_t)((row & 127) >> 4) * 512 +
                         ((((k0 & 31) >> 3) * 16 + (row & 15)) * 8) + (k0 & 7);
            *(unsigned long long*)&ws[idx] = pack4(v[0], v[1], v[2], v[3]);
        }
    }
}

// ============================ main ============================
// 512 blocks x 512 thr (8 waves). Block = 256 B-rows x 2 channels (N=256).
// Traffic-minimal: W1 read 4x (64MB), X read 64x (128MB) -> 192MB CU-ingress
// vs 0.5-1 GB in all prior rounds. Per-XCD working set (2MB W1 + 1MB X) fits
// the 4MB XCD L2 -> re-reads are L2 hits. Staging via linear global_load_lds
// of frag-packed tiles (no VALU, no bank conflicts). GEMM2 is wave-private.
// LDS 64KB: X dbuf [0,16K)ushorts, W dbuf [16K,32K)ushorts; 8KB/wave slots
// overlay for GEMM2.
__global__ __launch_bounds__(512, 2) void bank_main(
    const float* __restrict__ pb1, const float* __restrict__ pb2,
    const float* __restrict__ nb1, const float* __restrict__ nb2,
    const unsigned short* __restrict__ ws,
    float* __restrict__ out)
{
    __shared__ unsigned short smem[32768];   // 64 KB

    // p -> xcd (p&7); within XCD: 8 c-pairs x 4 btiles x 2 banks (64 blocks,
    // all co-resident at 2 blocks/CU x 32 CU).
    const int p     = blockIdx.x;          // 0..511
    const int xcd   = p & 7;
    const int rank  = p >> 3;              // 0..63
    const int cg    = rank & 7;            // c-pair within xcd
    const int btile = (rank >> 3) & 3;
    const int bank  = rank >> 5;
    const int c0    = xcd * 16 + cg * 2;   // block covers c0, c0+1
    const int bbase = btile * 256;

    const int t    = threadIdx.x;
    const int wave = t >> 6;               // 0..7
    const int lane = t & 63;
    const int lr   = lane & 15;
    const int lkg  = lane >> 4;
    const int wm   = wave >> 1;            // 0..3: 64-row slice
    const int wn   = wave & 1;             // 0..1: which channel

    const unsigned short* xsrc0 = ws + WS_X_OFF + (size_t)(btile * 2) * 65536;
    const unsigned short* xsrc1 = xsrc0 + 65536;
    const unsigned short* wsrc0 = ws + (size_t)(bank * 128 + c0) * WS_W1_STRIDE;
    const unsigned short* wsrc1 = wsrc0 + WS_W1_STRIDE;

    f32x4 acc[4][8];
#pragma unroll
    for (int mi = 0; mi < 4; ++mi)
#pragma unroll
        for (int ni = 0; ni < 8; ++ni) acc[mi][ni] = (f32x4){0.f, 0.f, 0.f, 0.f};

    // stage one K-step (32KB): 4 linear g2l16 per thread
#define STAGE(KT, SEL)                                                          \
    {                                                                           \
        g2l16(xsrc0 + (KT) * 4096 + t * 8, &smem[(SEL) * 8192 + t * 8]);        \
        g2l16(xsrc1 + (KT) * 4096 + t * 8, &smem[(SEL) * 8192 + 4096 + t * 8]); \
        g2l16(wsrc0 + (KT) * 4096 + t * 8, &smem[16384 + (SEL) * 8192 + t * 8]);\
        g2l16(wsrc1 + (KT) * 4096 + t * 8,                                      \
              &smem[16384 + (SEL) * 8192 + 4096 + t * 8]);                      \
    }

    STAGE(0, 0);
    __syncthreads();

    for (int kt = 0; kt < NKT; ++kt) {
        const int sel = kt & 1;
        if (kt < NKT - 1) STAGE(kt + 1, sel ^ 1);

        const unsigned short* Xb = &smem[sel * 8192 + (wm >> 1) * 4096 +
                                         (wm & 1) * 2048 + lane * 8];
        const unsigned short* Wb = &smem[16384 + sel * 8192 + wn * 4096 + lane * 8];
        bf16x8 af[4], bfr[8];
#pragma unroll
        for (int mi = 0; mi < 4; ++mi) af[mi] = ld16(Xb + mi * 512);
#pragma unroll
        for (int ni = 0; ni < 8; ++ni) bfr[ni] = ld16(Wb + ni * 512);

        __builtin_amdgcn_s_setprio(1);
#pragma unroll
        for (int mi = 0; mi < 4; ++mi)
#pragma unroll
            for (int ni = 0; ni < 8; ++ni)
                acc[mi][ni] = __builtin_amdgcn_mfma_f32_16x16x32_bf16(
                    af[mi], bfr[ni], acc[mi][ni], 0, 0, 0);
        __builtin_amdgcn_s_setprio(0);
        __syncthreads();
    }

    // ---- epilogue: wave-private. c for this wave: ----
    const int cw   = c0 + wn;
    const int pw   = bank * 128 + cw;
    const float* b1c = (bank ? nb1 : pb1) + cw * HID;
    const float* b2c = (bank ? nb2 : pb2) + cw * EMB;
    float b1v[8];
#pragma unroll
    for (int ni = 0; ni < 8; ++ni) b1v[ni] = b1c[ni * 16 + lr];
    float b2v[2];
#pragma unroll
    for (int ei = 0; ei < 2; ++ei) b2v[ei] = b2c[ei * 16 + lr];

    // W2 fragments (frag-packed, coalesced)
    const unsigned short* w2base = ws + WS_W2_OFF + (size_t)pw * 4096 + lane * 8;
    bf16x8 w2f[2][4];
#pragma unroll
    for (int k2 = 0; k2 < 4; ++k2)
#pragma unroll
        for (int ei = 0; ei < 2; ++ei)
            w2f[ei][k2] = ld16(w2base + k2 * 1024 + ei * 512);

    unsigned short* slot = &smem[wave * 4096];   // 8 KB private
    f32x4 acc2[4][2];
#pragma unroll
    for (int m2 = 0; m2 < 4; ++m2)
#pragma unroll
        for (int ei = 0; ei < 2; ++ei) acc2[m2][ei] = (f32x4){0.f, 0.f, 0.f, 0.f};

    // K-loop buffers fully consumed (last __syncthreads above) -> overlay OK.
#pragma unroll
    for (int ch = 0; ch < 2; ++ch) {
        // write H chunk [64 rows][64 cols] swizzled into private slot
#pragma unroll
        for (int mi = 0; mi < 4; ++mi) {
#pragma unroll
            for (int nq = 0; nq < 4; ++nq) {
                int ni = ch * 4 + nq;
                int lh = nq * 16 + lr;           // local col 0..63
#pragma unroll
                for (int j = 0; j < 4; ++j) {
                    int r = mi * 16 + lkg * 4 + j;
                    float v = fmaxf(acc[mi][ni][j] + b1v[ni], 0.f);
                    slot[r * 64 + ((((lh >> 3) & 7) ^ (r & 7)) << 3) + (lh & 7)] = f2b(v);
                }
            }
        }
        // read back as A-fragments and accumulate GEMM2 (same wave: in-order LDS)
#pragma unroll
        for (int kk = 0; kk < 2; ++kk) {
            int k2 = ch * 2 + kk;
            bf16x8 a2[4];
#pragma unroll
            for (int m2 = 0; m2 < 4; ++m2) {
                int r = m2 * 16 + lr;
                a2[m2] = ld16(&slot[r * 64 + (((kk * 4 + lkg) ^ (r & 7)) << 3)]);
            }
#pragma unroll
            for (int m2 = 0; m2 < 4; ++m2)
#pragma unroll
                for (int ei = 0; ei < 2; ++ei)
                    acc2[m2][ei] = __builtin_amdgcn_mfma_f32_16x16x32_bf16(
                        a2[m2], w2f[ei][k2], acc2[m2][ei], 0, 0, 0);
        }
    }

    float* outb = out + (size_t)bank * B_TOT * EMB * C_DIM;
#pragma unroll
    for (int m2 = 0; m2 < 4; ++m2) {
#pragma unroll
        for (int ei = 0; ei < 2; ++ei) {
            int e = ei * 16 + lr;
#pragma unroll
            for (int j = 0; j < 4; ++j) {
                int brow = bbase + wm * 64 + m2 * 16 + lkg * 4 + j;
                outb[((size_t)brow * EMB + e) * C_DIM + cw] = acc2[m2][ei][j] + b2v[ei];
            }
        }
    }
#undef STAGE
}

// ===================== fallback (round-10 single kernel, known-good) ============
#define XS_LD 68
#define W1_LD 68
#define HS_LD 132
#define W2_LD 132
__device__ __forceinline__ bf16x8 load8u(const unsigned short* p) {
    union { unsigned long long q[2]; bf16x8 v; } u;
    u.q[0] = *(const unsigned long long*)(p);
    u.q[1] = *(const unsigned long long*)(p + 4);
    return u.v;
}
__global__ __launch_bounds__(256, 2) void bank_fallback(
    const float* __restrict__ x,
    const float* __restrict__ pW1, const float* __restrict__ pb1,
    const float* __restrict__ pW2, const float* __restrict__ pb2,
    const float* __restrict__ nW1, const float* __restrict__ nb1,
    const float* __restrict__ nW2, const float* __restrict__ nb2,
    float* __restrict__ out)
{
    __shared__ unsigned short Xs [128][XS_LD];
    __shared__ unsigned short W1T[HID][W1_LD];
    __shared__ unsigned short Hs [128][HS_LD];
    __shared__ unsigned short W2T[EMB][W2_LD];
    int p = blockIdx.x;
    int xcd = p & 7, rank = p >> 3;
    int c = xcd * 16 + (rank & 15);
    int btile = (rank >> 4) & 7;
    int bank = rank >> 7;
    int bbase = btile * 128;
    const float* W1c = (bank ? nW1 : pW1) + (size_t)c * IN_DIM * HID;
    const float* b1c = (bank ? nb1 : pb1) + c * HID;
    const float* W2c = (bank ? nW2 : pW2) + (size_t)c * HID * EMB;
    const float* b2c = (bank ? nb2 : pb2) + c * EMB;
    float* outb = out + (size_t)bank * B_TOT * EMB * C_DIM;
    int t = threadIdx.x, wave = t >> 6, lane = t & 63;
    int lr = lane & 15, lkg = lane >> 4, wm = wave >> 1, wn = wave & 1;
    {
        int e0 = (t & 7) * 4, h0 = (t >> 3) * 4;
        f32x4 L0 = *(const f32x4*)&W2c[(h0 + 0) * EMB + e0];
        f32x4 L1 = *(const f32x4*)&W2c[(h0 + 1) * EMB + e0];
        f32x4 L2 = *(const f32x4*)&W2c[(h0 + 2) * EMB + e0];
        f32x4 L3 = *(const f32x4*)&W2c[(h0 + 3) * EMB + e0];
#pragma unroll
        for (int j = 0; j < 4; ++j)
            *(unsigned long long*)&W2T[e0 + j][h0] = pack4(L0[j], L1[j], L2[j], L3[j]);
    }
    float b1v[4];
#pragma unroll
    for (int ni = 0; ni < 4; ++ni) b1v[ni] = b1c[wn * 64 + ni * 16 + lr];
    float b2v[2];
#pragma unroll
    for (int ei = 0; ei < 2; ++ei) b2v[ei] = b2c[ei * 16 + lr];
    f32x4 acc[4][4];
#pragma unroll
    for (int mi = 0; mi < 4; ++mi)
#pragma unroll
        for (int ni = 0; ni < 4; ++ni) acc[mi][ni] = (f32x4){0.f, 0.f, 0.f, 0.f};
    for (int kt = 0; kt < 8; ++kt) {
        int kb = kt * 64;
#pragma unroll
        for (int w8 = 0; w8 < 8; ++w8) {
            int f = w8 * 256 + t;
            int row = f >> 4, col = (f & 15) * 4;
            f32x4 v = *(const f32x4*)&x[(size_t)(bbase + row) * IN_DIM + kb + col];
            *(unsigned long long*)&Xs[row][col] = pack4(v[0], v[1], v[2], v[3]);
        }
#pragma unroll
        for (int g = 0; g < 2; ++g) {
            int s = g * 256 + t;
            int k0 = (s >> 5) * 4, h0 = (s & 31) * 4;
            const float* src = &W1c[(size_t)(kb + k0) * HID + h0];
            f32x4 L0 = *(const f32x4*)(src + 0 * HID);
            f32x4 L1 = *(const f32x4*)(src + 1 * HID);
            f32x4 L2 = *(const f32x4*)(src + 2 * HID);
            f32x4 L3 = *(const f32x4*)(src + 3 * HID);
#pragma unroll
            for (int j = 0; j < 4; ++j)
                *(unsigned long long*)&W1T[h0 + j][k0] = pack4(L0[j], L1[j], L2[j], L3[j]);
        }
        __syncthreads();
#pragma unroll
        for (int ki = 0; ki < 2; ++ki) {
            int kcol = ki * 32 + lkg * 8;
            bf16x8 af[4], bfr[4];
#pragma unroll
            for (int mi = 0; mi < 4; ++mi) af[mi] = load8u(&Xs[wm * 64 + mi * 16 + lr][kcol]);
#pragma unroll
            for (int ni = 0; ni < 4; ++ni) bfr[ni] = load8u(&W1T[wn * 64 + ni * 16 + lr][kcol]);
#pragma unroll
            for (int mi = 0; mi < 4; ++mi)
#pragma unroll
                for (int ni = 0; ni < 4; ++ni)
                    acc[mi][ni] = __builtin_amdgcn_mfma_f32_16x16x32_bf16(
                        af[mi], bfr[ni], acc[mi][ni], 0, 0, 0);
        }
        __syncthreads();
    }
#pragma unroll
    for (int mi = 0; mi < 4; ++mi) {
        int row = wm * 64 + mi * 16 + lkg * 4;
#pragma unroll
        for (int ni = 0; ni < 4; ++ni) {
            int col = wn * 64 + ni * 16 + lr;
#pragma unroll
            for (int j = 0; j < 4; ++j)
                Hs[row + j][col] = f2b(fmaxf(acc[mi][ni][j] + b1v[ni], 0.f));
        }
    }
    __syncthreads();
    f32x4 acc2[2][2];
#pragma unroll
    for (int m2 = 0; m2 < 2; ++m2)
#pragma unroll
        for (int ei = 0; ei < 2; ++ei) acc2[m2][ei] = (f32x4){0.f, 0.f, 0.f, 0.f};
    int rb = wave * 32;
#pragma unroll
    for (int k2 = 0; k2 < 4; ++k2) {
        int kcol = k2 * 32 + lkg * 8;
        bf16x8 a2[2], b2f[2];
#pragma unroll
        for (int m2 = 0; m2 < 2; ++m2) a2[m2] = load8u(&Hs[rb + m2 * 16 + lr][kcol]);
#pragma unroll
        for (int ei = 0; ei < 2; ++ei) b2f[ei] = load8u(&W2T[ei * 16 + lr][kcol]);
#pragma unroll
        for (int m2 = 0; m2 < 2; ++m2)
#pragma unroll
            for (int ei = 0; ei < 2; ++ei)
                acc2[m2][ei] = __builtin_amdgcn_mfma_f32_16x16x32_bf16(
                    a2[m2], b2f[ei], acc2[m2][ei], 0, 0, 0);
    }
#pragma unroll
    for (int m2 = 0; m2 < 2; ++m2)
#pragma unroll
        for (int ei = 0; ei < 2; ++ei) {
            int e = ei * 16 + lr;
#pragma unroll
            for (int j = 0; j < 4; ++j) {
                int brow = bbase + rb + m2 * 16 + lkg * 4 + j;
                outb[((size_t)brow * EMB + e) * C_DIM + c] = acc2[m2][ei][j] + b2v[ei];
            }
        }
}

extern "C" void kernel_launch(void* const* d_in, const int* in_sizes, int n_in,
                              void* d_out, int out_size, void* d_ws, size_t ws_size,
                              hipStream_t stream) {
    const float* x   = (const float*)d_in[0];
    const float* pW1 = (const float*)d_in[1];
    const float* pb1 = (const float*)d_in[2];
    const float* pW2 = (const float*)d_in[3];
    const float* pb2 = (const float*)d_in[4];
    const float* nW1 = (const float*)d_in[5];
    const float* nb1 = (const float*)d_in[6];
    const float* nW2 = (const float*)d_in[7];
    const float* nb2 = (const float*)d_in[8];
    float* out = (float*)d_out;

    if (ws_size >= WS_NEEDED_B) {
        unsigned short* ws = (unsigned short*)d_ws;
        prepass<<<dim3(1024), dim3(256), 0, stream>>>(x, pW1, pW2, nW1, nW2, ws);
        bank_main<<<dim3(512), dim3(512), 0, stream>>>(pb1, pb2, nb1, nb2, ws, out);
    } else {
        bank_fallback<<<dim3(2048), dim3(256), 0, stream>>>(
            x, pW1, pb1, pW2, pb2, nW1, nb1, nW2, nb2, out);
    }
}